// Round 1
// baseline (664.305 us; speedup 1.0000x reference)
//
#include <hip/hip_runtime.h>
#include <math.h>
#include <float.h>

#define NTOK  16384
#define DDIM  2048
#define TOPK  8
#define GR    16

#define MB    32          // rows per block
#define KB    64          // K chunk
#define WS_ST 148         // W-tile LDS stride (floats), mult of 4 for b128 alignment
#define XS_ST 34          // x-tile LDS stride (floats), even for b64 alignment
#define S_ST  148         // S-tile stride
#define LDSF  (KB*WS_ST + KB*XS_ST)   // 9472 + 2176 = 11648 floats = 46592 B

// Insert (nv,nk) into descending top-8 list; ties broken by smaller index first
// (matches jax.lax.top_k stability).
__device__ __forceinline__ void insert8(float v[TOPK], int id[TOPK], float nv, int nk)
{
    bool beats_last = (nv > v[TOPK-1]) || (nv == v[TOPK-1] && nk < id[TOPK-1]);
    if (!beats_last) return;
    v[TOPK-1] = nv; id[TOPK-1] = nk;
    #pragma unroll
    for (int q = TOPK-1; q > 0; --q) {
        bool sw = (v[q] > v[q-1]) || (v[q] == v[q-1] && id[q] < id[q-1]);
        if (sw) {
            float tv = v[q]; v[q] = v[q-1]; v[q-1] = tv;
            int   ti = id[q]; id[q] = id[q-1]; id[q-1] = ti;
        }
    }
}

__global__ __launch_bounds__(256, 2) void pk_router(
    const float* __restrict__ x,  const float* __restrict__ W1,
    const float* __restrict__ W2, const float* __restrict__ Wg,
    const float* __restrict__ G,  float* __restrict__ out)
{
    __shared__ float lds[LDSF];
    const int t    = threadIdx.x;
    const int rb   = blockIdx.x * MB;
    const int rowg = t & 15;   // 16 row groups x 2 rows
    const int colg = t >> 4;   // 16 col groups: 4 s1-cols + 4 s2-cols + 1 qg-col

    float acc1[2][4];
    float acc2[2][4];
    float accg[2];
    #pragma unroll
    for (int r = 0; r < 2; ++r) {
        #pragma unroll
        for (int u = 0; u < 4; ++u) { acc1[r][u] = 0.f; acc2[r][u] = 0.f; }
        accg[r] = 0.f;
    }

    float* xs = lds + KB*WS_ST;

    for (int kb = 0; kb < DDIM; kb += KB) {
        // stage x[rb..rb+31][kb..kb+63] -> xs[k][row]  (k-major)
        #pragma unroll
        for (int i = 0; i < 2; ++i) {
            const int idx = t + 256*i;
            const int r   = idx >> 4;      // 0..31
            const int k4  = idx & 15;      // 0..15
            const float4 v = *(const float4*)(x + (size_t)(rb + r)*DDIM + kb + k4*4);
            xs[(k4*4+0)*XS_ST + r] = v.x;
            xs[(k4*4+1)*XS_ST + r] = v.y;
            xs[(k4*4+2)*XS_ST + r] = v.z;
            xs[(k4*4+3)*XS_ST + r] = v.w;
        }
        // stage W rows 0..143 (W1|W2|Wg) cols kb..kb+63 -> ws[k][c] (k-major)
        #pragma unroll
        for (int i = 0; i < 9; ++i) {
            const int idx = t + 256*i;
            const int c   = idx >> 4;      // 0..143
            const int k4  = idx & 15;
            const float* src = (c < 64)  ? (W1 + (size_t)c*DDIM)
                             : (c < 128) ? (W2 + (size_t)(c-64)*DDIM)
                                         : (Wg + (size_t)(c-128)*DDIM);
            const float4 v = *(const float4*)(src + kb + k4*4);
            lds[(k4*4+0)*WS_ST + c] = v.x;
            lds[(k4*4+1)*WS_ST + c] = v.y;
            lds[(k4*4+2)*WS_ST + c] = v.z;
            lds[(k4*4+3)*WS_ST + c] = v.w;
        }
        __syncthreads();

        #pragma unroll 8
        for (int kk = 0; kk < KB; ++kk) {
            const float2 a  = *(const float2*)(xs + kk*XS_ST + rowg*2);
            const float4 b1 = *(const float4*)(lds + kk*WS_ST + colg*4);
            const float4 b2 = *(const float4*)(lds + kk*WS_ST + 64 + colg*4);
            const float  bg = lds[kk*WS_ST + 128 + colg];
            acc1[0][0] += a.x*b1.x; acc1[0][1] += a.x*b1.y;
            acc1[0][2] += a.x*b1.z; acc1[0][3] += a.x*b1.w;
            acc1[1][0] += a.y*b1.x; acc1[1][1] += a.y*b1.y;
            acc1[1][2] += a.y*b1.z; acc1[1][3] += a.y*b1.w;
            acc2[0][0] += a.x*b2.x; acc2[0][1] += a.x*b2.y;
            acc2[0][2] += a.x*b2.z; acc2[0][3] += a.x*b2.w;
            acc2[1][0] += a.y*b2.x; acc2[1][1] += a.y*b2.y;
            acc2[1][2] += a.y*b2.z; acc2[1][3] += a.y*b2.w;
            accg[0] += a.x*bg;
            accg[1] += a.y*bg;
        }
        __syncthreads();
    }

    // spill S tile [32][144] into LDS (aliases GEMM tiles; safe after barrier)
    float* S = lds;
    #pragma unroll
    for (int rr = 0; rr < 2; ++rr) {
        const int r = rowg*2 + rr;
        #pragma unroll
        for (int u = 0; u < 4; ++u) {
            S[r*S_ST + colg*4 + u]      = acc1[rr][u];
            S[r*S_ST + 64 + colg*4 + u] = acc2[rr][u];
        }
        S[r*S_ST + 128 + colg] = accg[rr];
    }
    __syncthreads();

    // ---- phase 3a: write select_scores[rb..rb+31][0..4095], coalesced float4
    // out layout: [idx NTOK*8][weights NTOK*8][scores NTOK*4096]
    const size_t scoreBase = (size_t)NTOK*2*TOPK + (size_t)rb*4096;
    const int i0 = t >> 4;         // s1 sub-index
    const int j4 = (t & 15)*4;     // s2 sub-index (float4)
    for (int r = 0; r < MB; ++r) {
        const float4 s2v = *(const float4*)(S + r*S_ST + 64 + j4);
        #pragma unroll
        for (int q = 0; q < 4; ++q) {
            const float s1v = S[r*S_ST + q*16 + i0];
            float4 o;
            o.x = s1v + s2v.x; o.y = s1v + s2v.y;
            o.z = s1v + s2v.z; o.w = s1v + s2v.w;
            *(float4*)(out + scoreBase + (size_t)r*4096 + (size_t)(q*1024 + t*4)) = o;
        }
    }

    // ---- phase 3b: per-row top-8 + gate + softmax (one lane per row)
    if (t < MB) {
        const float* Srow = S + t*S_ST;
        float v1[TOPK], v2[TOPK]; int i1[TOPK], i2[TOPK];
        #pragma unroll
        for (int e = 0; e < TOPK; ++e) { v1[e] = -FLT_MAX; v2[e] = -FLT_MAX; i1[e] = 1<<30; i2[e] = 1<<30; }
        for (int i = 0; i < 64; ++i) insert8(v1, i1, Srow[i], i);
        for (int j = 0; j < 64; ++j) insert8(v2, i2, Srow[64 + j], j);

        // top-8 of the 64 candidate sums; the true top-8 of s1[i]+s2[j] is
        // contained in top8(s1) x top8(s2) (standard product-key argument,
        // valid under (value desc, index asc) ordering).
        float cv[TOPK]; int ck[TOPK];
        #pragma unroll
        for (int e = 0; e < TOPK; ++e) { cv[e] = -FLT_MAX; ck[e] = 1<<30; }
        #pragma unroll
        for (int a = 0; a < TOPK; ++a) {
            #pragma unroll
            for (int b = 0; b < TOPK; ++b)
                insert8(cv, ck, v1[a] + v2[b], i1[a]*64 + i2[b]);
        }

        float qg[GR];
        #pragma unroll
        for (int u = 0; u < GR; ++u) qg[u] = Srow[128 + u];

        float comb[TOPK];
        #pragma unroll
        for (int e = 0; e < TOPK; ++e) {
            const float* gp = G + (size_t)ck[e]*GR;
            float dot = 0.f;
            #pragma unroll
            for (int u = 0; u < GR; ++u) dot += qg[u] * gp[u];
            comb[e] = cv[e] + dot;
        }
        float m = comb[0];
        #pragma unroll
        for (int e = 1; e < TOPK; ++e) m = fmaxf(m, comb[e]);
        float w[TOPK]; float s = 0.f;
        #pragma unroll
        for (int e = 0; e < TOPK; ++e) { w[e] = expf(comb[e] - m); s += w[e]; }
        const float inv = 1.f / s;

        const size_t row = (size_t)rb + t;
        #pragma unroll
        for (int e = 0; e < TOPK; ++e) {
            out[row*TOPK + e] = (float)ck[e];                       // indices as float
            out[(size_t)NTOK*TOPK + row*TOPK + e] = w[e]*inv;       // weights
        }
    }
}

extern "C" void kernel_launch(void* const* d_in, const int* in_sizes, int n_in,
                              void* d_out, int out_size, void* d_ws, size_t ws_size,
                              hipStream_t stream)
{
    const float* x  = (const float*)d_in[0];
    const float* W1 = (const float*)d_in[1];
    const float* W2 = (const float*)d_in[2];
    const float* Wg = (const float*)d_in[3];
    const float* G  = (const float*)d_in[4];
    float* out = (float*)d_out;

    pk_router<<<dim3(NTOK/MB), dim3(256), 0, stream>>>(x, W1, W2, Wg, G, out);
}